// Round 1
// 770.534 us; speedup vs baseline: 1.0067x; 1.0067x over previous
//
#include <hip/hip_runtime.h>

#define LEN 256
#define WAVES_PER_BLOCK 4
#define ROWS_PER_BLOCK (WAVES_PER_BLOCK * 2)   // 2 rows per wave

// Reductions across a 32-lane half-wave (masks <=16 never cross the
// 32-lane ds_swizzle group, so both halves reduce independently).
__device__ __forceinline__ float half_max(float v) {
#pragma unroll
    for (int m = 16; m >= 1; m >>= 1) v = fmaxf(v, __shfl_xor(v, m, 64));
    return v;
}

__device__ __forceinline__ float half_sum(float v) {
#pragma unroll
    for (int m = 16; m >= 1; m >>= 1) v += __shfl_xor(v, m, 64);
    return v;
}

// FWHT-256 with one row per 32-lane half-wave.
// Lane sl (0..31) holds elements {4*sl..4*sl+3} in r[0..3] and
// {128+4*sl..128+4*sl+3} in r[4..7]. Index bits 0,1,7 are in-lane;
// bits 2..6 are lane bits -> xor masks 1..16 (single ds_swizzle each,
// no 32-lane-crossing shuffles anywhere).
__device__ __forceinline__ void fwht256(float r[8], int sl) {
    // bit 0
    float t0 = r[0] + r[1], t1 = r[0] - r[1];
    float t2 = r[2] + r[3], t3 = r[2] - r[3];
    float t4 = r[4] + r[5], t5 = r[4] - r[5];
    float t6 = r[6] + r[7], t7 = r[6] - r[7];
    // bit 1
    float u0 = t0 + t2, u1 = t1 + t3, u2 = t0 - t2, u3 = t1 - t3;
    float u4 = t4 + t6, u5 = t5 + t7, u6 = t4 - t6, u7 = t5 - t7;
    // bit 7 (pairs the two float4 groups)
    r[0] = u0 + u4; r[1] = u1 + u5; r[2] = u2 + u6; r[3] = u3 + u7;
    r[4] = u0 - u4; r[5] = u1 - u5; r[6] = u2 - u6; r[7] = u3 - u7;
    // bits 2..6: cross-lane butterflies within the half-wave
#pragma unroll
    for (int m = 1; m <= 16; m <<= 1) {
        float s = (sl & m) ? -1.0f : 1.0f;
#pragma unroll
        for (int j = 0; j < 8; ++j) {
            float o = __shfl_xor(r[j], m, 64);
            r[j] = fmaf(s, r[j], o);  // bit=0: self+other ; bit=1: other-self
        }
    }
}

__device__ __forceinline__ void log_softmax_store(const float v[8],
                                                  float* __restrict__ row_out,
                                                  int sl) {
    float mx = fmaxf(fmaxf(fmaxf(v[0], v[1]), fmaxf(v[2], v[3])),
                     fmaxf(fmaxf(v[4], v[5]), fmaxf(v[6], v[7])));
    mx = half_max(mx);
    float d[8];
    float s = 0.0f;
#pragma unroll
    for (int j = 0; j < 8; ++j) { d[j] = v[j] - mx; s += __expf(d[j]); }
    s = half_sum(s);
    float ls = __logf(s);
    float4 o0 = make_float4(d[0] - ls, d[1] - ls, d[2] - ls, d[3] - ls);
    float4 o1 = make_float4(d[4] - ls, d[5] - ls, d[6] - ls, d[7] - ls);
    ((float4*)row_out)[sl] = o0;        // contiguous 512B per half-wave
    ((float4*)row_out)[32 + sl] = o1;   // contiguous 512B per half-wave
}

__global__ __launch_bounds__(256) void group_recombine_kernel(
        const float* __restrict__ b0, const float* __restrict__ b1,
        const float* __restrict__ mk, float* __restrict__ out, int rows) {
    const int wave = threadIdx.x >> 6;
    const int lane = threadIdx.x & 63;
    const int sl = lane & 31;          // lane within half-wave
    const int h = lane >> 5;           // which row of the wave's pair
    const int row = blockIdx.x * ROWS_PER_BLOCK + wave * 2 + h;
    if (row >= rows) return;

    const size_t base = (size_t)row * LEN;
    const size_t stride = (size_t)rows * LEN;

    // Issue all six loads up front so HBM latency overlaps the first
    // shuffle chains.
    const float4* p0 = (const float4*)(b0 + base);
    const float4* p1 = (const float4*)(b1 + base);
    const float4* p2 = (const float4*)(mk + base);
    float4 a0 = p0[sl], a1 = p0[32 + sl];
    float4 c0 = p1[sl], c1 = p1[32 + sl];
    float4 e0 = p2[sl], e1 = p2[32 + sl];

    // ---- share 0 ----
    float w0[8] = {a0.x, a0.y, a0.z, a0.w, a1.x, a1.y, a1.z, a1.w};
    log_softmax_store(w0, out + base, sl);
    fwht256(w0, sl);

    // ---- share 1 ----
    float w1[8] = {c0.x, c0.y, c0.z, c0.w, c1.x, c1.y, c1.z, c1.w};
    log_softmax_store(w1, out + stride + base, sl);
    fwht256(w1, sl);

    // ---- share 2 ----
    float w2[8] = {e0.x, e0.y, e0.z, e0.w, e1.x, e1.y, e1.z, e1.w};
    log_softmax_store(w2, out + 2 * stride + base, sl);
    fwht256(w2, sl);

    // ---- WH-domain product, inverse transform, scale 1/256 ----
    float pr[8];
#pragma unroll
    for (int j = 0; j < 8; ++j) pr[j] = w0[j] * w1[j] * w2[j];
    fwht256(pr, sl);
#pragma unroll
    for (int j = 0; j < 8; ++j) pr[j] *= (1.0f / 256.0f);
    log_softmax_store(pr, out + 3 * stride + base, sl);
}

extern "C" void kernel_launch(void* const* d_in, const int* in_sizes, int n_in,
                              void* d_out, int out_size, void* d_ws, size_t ws_size,
                              hipStream_t stream) {
    const float* b0 = (const float*)d_in[0];
    const float* b1 = (const float*)d_in[1];
    const float* mk = (const float*)d_in[2];
    float* out = (float*)d_out;
    const int rows = in_sizes[0] / LEN;  // 131072
    dim3 grid((rows + ROWS_PER_BLOCK - 1) / ROWS_PER_BLOCK);
    dim3 block(64 * WAVES_PER_BLOCK);
    group_recombine_kernel<<<grid, block, 0, stream>>>(b0, b1, mk, out, rows);
}